// Round 1
// baseline (675.177 us; speedup 1.0000x reference)
//
#include <hip/hip_runtime.h>

#define DHID 64

// ---------- CSR build ----------
__global__ void k_init(int* __restrict__ cnt, int* __restrict__ fill, int n) {
  int i = blockIdx.x * blockDim.x + threadIdx.x;
  if (i < n) { cnt[i] = 1; fill[i] = 0; }  // cnt=1 pre-counts the self-loop
}

__global__ void k_hist(const int* __restrict__ dst, int* __restrict__ cnt, int E) {
  int i = blockIdx.x * blockDim.x + threadIdx.x;
  if (i < E) atomicAdd(&cnt[dst[i]], 1);
}

// each block scans a 1024-element chunk (256 threads x 4 elems), in-place exclusive
__global__ void k_scan_block(int* __restrict__ buf, int n, int* __restrict__ bsum) {
  __shared__ int lds[256];
  int tid = threadIdx.x;
  int base = blockIdx.x * 1024 + tid * 4;
  int a0 = (base + 0) < n ? buf[base + 0] : 0;
  int a1 = (base + 1) < n ? buf[base + 1] : 0;
  int a2 = (base + 2) < n ? buf[base + 2] : 0;
  int a3 = (base + 3) < n ? buf[base + 3] : 0;
  int s = a0 + a1 + a2 + a3;
  lds[tid] = s; __syncthreads();
  for (int off = 1; off < 256; off <<= 1) {
    int t = (tid >= off) ? lds[tid - off] : 0;
    __syncthreads();
    lds[tid] += t;
    __syncthreads();
  }
  int excl = lds[tid] - s;
  if ((base + 0) < n) buf[base + 0] = excl; excl += a0;
  if ((base + 1) < n) buf[base + 1] = excl; excl += a1;
  if ((base + 2) < n) buf[base + 2] = excl; excl += a2;
  if ((base + 3) < n) buf[base + 3] = excl;
  if (tid == 255) bsum[blockIdx.x] = lds[255];
}

// inclusive scan of up to 128 block sums, one wave
__global__ void k_scan_mid(int* __restrict__ bsum, int nb) {
  int lane = threadIdx.x;
  int v0 = (lane < nb) ? bsum[lane] : 0;
  #pragma unroll
  for (int off = 1; off < 64; off <<= 1) { int t = __shfl_up(v0, off, 64); if (lane >= off) v0 += t; }
  int v1 = (64 + lane) < nb ? bsum[64 + lane] : 0;
  #pragma unroll
  for (int off = 1; off < 64; off <<= 1) { int t = __shfl_up(v1, off, 64); if (lane >= off) v1 += t; }
  v1 += __shfl(v0, 63, 64);
  if (lane < nb) bsum[lane] = v0;
  if ((64 + lane) < nb) bsum[64 + lane] = v1;
}

__global__ void k_scan_add(int* __restrict__ buf, int n, const int* __restrict__ bsum, int nb) {
  int i = blockIdx.x * blockDim.x + threadIdx.x;
  if (i < n) { int c = i >> 10; if (c > 0) buf[i] += bsum[c - 1]; }
  if (i == 0) buf[n] = bsum[nb - 1];
}

__global__ void k_fill(const int* __restrict__ src, const int* __restrict__ dst,
                       const int* __restrict__ roff, int* __restrict__ fill,
                       int* __restrict__ csr, int E, int N) {
  int i = blockIdx.x * blockDim.x + threadIdx.x;
  int T = E + N;
  if (i >= T) return;
  int s, d;
  if (i < E) { s = src[i]; d = dst[i]; } else { s = i - E; d = s; }
  int pos = roff[d] + atomicAdd(&fill[d], 1);
  csr[pos] = s;
}

// ---------- dense: h = x @ W ; as = h.a_src ; ad = h.a_dst ----------
__global__ void k_gemm(const float* __restrict__ x, const float* __restrict__ W,
                       const float* __restrict__ a_s, const float* __restrict__ a_d,
                       float* __restrict__ h, float* __restrict__ asb, float* __restrict__ adb,
                       int N, int K) {
  __shared__ float Wl[128 * DHID];
  for (int i = threadIdx.x; i < K * DHID; i += blockDim.x) Wl[i] = W[i];
  __syncthreads();
  int lane = threadIdx.x & 63;
  int wid = blockIdx.x * (blockDim.x >> 6) + (threadIdx.x >> 6);
  int nw = gridDim.x * (blockDim.x >> 6);
  float asv = a_s[lane], adv = a_d[lane];
  for (int n = wid; n < N; n += nw) {
    const float4* xr = (const float4*)(x + (long)n * K);
    float acc = 0.f;
    #pragma unroll 4
    for (int k4 = 0; k4 < (K >> 2); k4++) {
      float4 xv = xr[k4];
      int kb = k4 * 4;
      acc += xv.x * Wl[(kb + 0) * DHID + lane];
      acc += xv.y * Wl[(kb + 1) * DHID + lane];
      acc += xv.z * Wl[(kb + 2) * DHID + lane];
      acc += xv.w * Wl[(kb + 3) * DHID + lane];
    }
    h[(long)n * DHID + lane] = acc;
    float r1 = acc * asv, r2 = acc * adv;
    #pragma unroll
    for (int off = 32; off; off >>= 1) { r1 += __shfl_xor(r1, off, 64); r2 += __shfl_xor(r2, off, 64); }
    if (lane == 0) { asb[n] = r1; adb[n] = r2; }
  }
}

// ---------- sparse: fused softmax + aggregation, one wave per dst node ----------
// alpha = exp(l)/sum(exp(l)) is independent of the max-shift; logits are O(few),
// so exp() without max subtraction is safe in fp32.
__global__ void k_agg(const int* __restrict__ roff, const int* __restrict__ csr,
                      const float* __restrict__ asb, const float* __restrict__ adb,
                      const float* __restrict__ h, const float* __restrict__ b,
                      float* __restrict__ out, int N, int relu) {
  int lane = threadIdx.x & 63;
  int wid = blockIdx.x * (blockDim.x >> 6) + (threadIdx.x >> 6);
  int nw = gridDim.x * (blockDim.x >> 6);
  float bv = b[lane];
  for (int n = wid; n < N; n += nw) {
    int r0 = roff[n], r1 = roff[n + 1];
    float adn = adb[n];
    float acc = 0.f, den = 0.f;
    for (int i = r0; i < r1; i++) {
      int s = csr[i];                 // wave-uniform
      float l = asb[s] + adn;         // wave-uniform gather (L2-resident)
      l = fmaxf(l, 0.2f * l);         // leaky_relu(0.2)
      float e = __expf(l);
      den += e;
      acc += e * h[(long)s * DHID + lane];  // coalesced 256B gather
    }
    float o = acc / (den + 1e-16f) + bv;
    if (relu) o = fmaxf(o, 0.f);
    out[(long)n * DHID + lane] = o;
  }
}

extern "C" void kernel_launch(void* const* d_in, const int* in_sizes, int n_in,
                              void* d_out, int out_size, void* d_ws, size_t ws_size,
                              hipStream_t stream) {
  const float* x   = (const float*)d_in[0];
  const int*   ei  = (const int*)d_in[1];
  const float* W1  = (const float*)d_in[2];
  const float* as1 = (const float*)d_in[3];
  const float* ad1 = (const float*)d_in[4];
  const float* b1  = (const float*)d_in[5];
  const float* W2  = (const float*)d_in[6];
  const float* as2 = (const float*)d_in[7];
  const float* ad2 = (const float*)d_in[8];
  const float* b2  = (const float*)d_in[9];

  int N = in_sizes[0] / 128;
  int E = in_sizes[1] / 2;
  const int* srcp = ei;
  const int* dstp = ei + E;

  float* emb  = (float*)d_out;               // output 0: relu(layer1)
  float* out2 = emb + (size_t)N * DHID;      // output 1

  char* w = (char*)d_ws;
  int* roff = (int*)w;  w += (size_t)(N + 1) * 4;
  int* fill = (int*)w;  w += (size_t)N * 4;
  int* csr  = (int*)w;  w += (size_t)(E + N) * 4;
  int* bsum = (int*)w;  w += 512 * 4;
  float* h   = (float*)w; w += (size_t)N * DHID * 4;
  float* asb = (float*)w; w += (size_t)N * 4;
  float* adb = (float*)w; w += (size_t)N * 4;

  int nb = (N + 1023) / 1024;

  k_init<<<(N + 255) / 256, 256, 0, stream>>>(roff, fill, N);
  k_hist<<<(E + 255) / 256, 256, 0, stream>>>(dstp, roff, E);
  k_scan_block<<<nb, 256, 0, stream>>>(roff, N, bsum);
  k_scan_mid<<<1, 64, 0, stream>>>(bsum, nb);
  k_scan_add<<<(N + 255) / 256, 256, 0, stream>>>(roff, N, bsum, nb);
  k_fill<<<(E + N + 255) / 256, 256, 0, stream>>>(srcp, dstp, roff, fill, csr, E, N);

  // layer 1: h1 = x@W1 ; emb = relu(agg + b1)
  k_gemm<<<1024, 256, 0, stream>>>(x, W1, as1, ad1, h, asb, adb, N, 128);
  k_agg<<<2048, 256, 0, stream>>>(roff, csr, asb, adb, h, b1, emb, N, 1);
  // layer 2: h2 = emb@W2 ; out2 = agg + b2
  k_gemm<<<1024, 256, 0, stream>>>(emb, W2, as2, ad2, h, asb, adb, N, 64);
  k_agg<<<2048, 256, 0, stream>>>(roff, csr, asb, adb, h, b2, out2, N, 0);
}

// Round 2
// 460.634 us; speedup vs baseline: 1.4658x; 1.4658x over previous
//
#include <hip/hip_runtime.h>
#include <hip/hip_bf16.h>

#define DHID 64

// ---------- CSR build ----------
__global__ void k_init(int* __restrict__ cnt, int* __restrict__ fill, int n) {
  int i = blockIdx.x * blockDim.x + threadIdx.x;
  if (i < n) { cnt[i] = 1; fill[i] = 0; }  // cnt=1 pre-counts the self-loop
}

__global__ void k_hist(const int* __restrict__ dst, int* __restrict__ cnt, int E) {
  int i = blockIdx.x * blockDim.x + threadIdx.x;
  if (i < E) atomicAdd(&cnt[dst[i]], 1);
}

// each block scans a 1024-element chunk (256 threads x 4 elems), in-place exclusive
__global__ void k_scan_block(int* __restrict__ buf, int n, int* __restrict__ bsum) {
  __shared__ int lds[256];
  int tid = threadIdx.x;
  int base = blockIdx.x * 1024 + tid * 4;
  int a0 = (base + 0) < n ? buf[base + 0] : 0;
  int a1 = (base + 1) < n ? buf[base + 1] : 0;
  int a2 = (base + 2) < n ? buf[base + 2] : 0;
  int a3 = (base + 3) < n ? buf[base + 3] : 0;
  int s = a0 + a1 + a2 + a3;
  lds[tid] = s; __syncthreads();
  for (int off = 1; off < 256; off <<= 1) {
    int t = (tid >= off) ? lds[tid - off] : 0;
    __syncthreads();
    lds[tid] += t;
    __syncthreads();
  }
  int excl = lds[tid] - s;
  if ((base + 0) < n) buf[base + 0] = excl; excl += a0;
  if ((base + 1) < n) buf[base + 1] = excl; excl += a1;
  if ((base + 2) < n) buf[base + 2] = excl; excl += a2;
  if ((base + 3) < n) buf[base + 3] = excl;
  if (tid == 255) bsum[blockIdx.x] = lds[255];
}

// inclusive scan of up to 128 block sums, one wave
__global__ void k_scan_mid(int* __restrict__ bsum, int nb) {
  int lane = threadIdx.x;
  int v0 = (lane < nb) ? bsum[lane] : 0;
  #pragma unroll
  for (int off = 1; off < 64; off <<= 1) { int t = __shfl_up(v0, off, 64); if (lane >= off) v0 += t; }
  int v1 = (64 + lane) < nb ? bsum[64 + lane] : 0;
  #pragma unroll
  for (int off = 1; off < 64; off <<= 1) { int t = __shfl_up(v1, off, 64); if (lane >= off) v1 += t; }
  v1 += __shfl(v0, 63, 64);
  if (lane < nb) bsum[lane] = v0;
  if ((64 + lane) < nb) bsum[64 + lane] = v1;
}

__global__ void k_scan_add(int* __restrict__ buf, int n, const int* __restrict__ bsum, int nb) {
  int i = blockIdx.x * blockDim.x + threadIdx.x;
  if (i < n) { int c = i >> 10; if (c > 0) buf[i] += bsum[c - 1]; }
  if (i == 0) buf[n] = bsum[nb - 1];
}

__global__ void k_fill(const int* __restrict__ src, const int* __restrict__ dst,
                       const int* __restrict__ roff, int* __restrict__ fill,
                       int* __restrict__ csr, int E, int N) {
  int i = blockIdx.x * blockDim.x + threadIdx.x;
  int T = E + N;
  if (i >= T) return;
  int s, d;
  if (i < E) { s = src[i]; d = dst[i]; } else { s = i - E; d = s; }
  int pos = roff[d] + atomicAdd(&fill[d], 1);
  csr[pos] = s;
}

// ---------- dense: h = x @ W (bf16 out) ; as = h.a_src ; ad = h.a_dst ----------
// 4-node blocking: each LDS weight read feeds 4 FMAs.
template<int K>
__global__ void k_gemm(const float* __restrict__ x, const float* __restrict__ W,
                       const float* __restrict__ a_s, const float* __restrict__ a_d,
                       __hip_bfloat16* __restrict__ hb, float* __restrict__ asb,
                       float* __restrict__ adb, int N) {
  __shared__ float Wl[K * DHID];
  for (int i = threadIdx.x; i < K * DHID; i += blockDim.x) Wl[i] = W[i];
  __syncthreads();
  int lane = threadIdx.x & 63;
  int wid = blockIdx.x * (blockDim.x >> 6) + (threadIdx.x >> 6);
  int nw = gridDim.x * (blockDim.x >> 6);
  float asv = a_s[lane], adv = a_d[lane];
  for (int n0 = wid * 4; n0 < N; n0 += nw * 4) {
    if (n0 + 4 <= N) {
      const float4* x0 = (const float4*)(x + (size_t)n0 * K);
      const float4* x1 = x0 + (K >> 2);
      const float4* x2 = x1 + (K >> 2);
      const float4* x3 = x2 + (K >> 2);
      float acc0 = 0.f, acc1 = 0.f, acc2 = 0.f, acc3 = 0.f;
      #pragma unroll 8
      for (int k4 = 0; k4 < (K >> 2); k4++) {
        float4 a = x0[k4], bq = x1[k4], c = x2[k4], d = x3[k4];
        #pragma unroll
        for (int kk = 0; kk < 4; kk++) {
          float w = Wl[(k4 * 4 + kk) * DHID + lane];
          acc0 += (&a.x)[kk]  * w;
          acc1 += (&bq.x)[kk] * w;
          acc2 += (&c.x)[kk]  * w;
          acc3 += (&d.x)[kk]  * w;
        }
      }
      float accs[4] = {acc0, acc1, acc2, acc3};
      #pragma unroll
      for (int t = 0; t < 4; t++) {
        float acc = accs[t];
        hb[(size_t)(n0 + t) * DHID + lane] = __float2bfloat16(acc);
        float r1 = acc * asv, r2 = acc * adv;
        #pragma unroll
        for (int off = 32; off; off >>= 1) { r1 += __shfl_xor(r1, off, 64); r2 += __shfl_xor(r2, off, 64); }
        if (lane == 0) { asb[n0 + t] = r1; adb[n0 + t] = r2; }
      }
    } else {
      for (int n = n0; n < N; n++) {
        const float4* xr = (const float4*)(x + (size_t)n * K);
        float acc = 0.f;
        for (int k4 = 0; k4 < (K >> 2); k4++) {
          float4 xv = xr[k4];
          #pragma unroll
          for (int kk = 0; kk < 4; kk++) acc += (&xv.x)[kk] * Wl[(k4 * 4 + kk) * DHID + lane];
        }
        hb[(size_t)n * DHID + lane] = __float2bfloat16(acc);
        float r1 = acc * asv, r2 = acc * adv;
        #pragma unroll
        for (int off = 32; off; off >>= 1) { r1 += __shfl_xor(r1, off, 64); r2 += __shfl_xor(r2, off, 64); }
        if (lane == 0) { asb[n] = r1; adb[n] = r2; }
      }
    }
  }
}

// ---------- sparse: fused softmax + aggregation, one wave per dst node ----------
// Phase 1 (lane-parallel): 64 edges' csr + asb gathers batched, e in registers.
// Phase 2: readlane-broadcast (s,e), 4 independent bf16 h-gathers in flight.
__global__ void k_agg(const int* __restrict__ roff, const int* __restrict__ csr,
                      const float* __restrict__ asb, const float* __restrict__ adb,
                      const __hip_bfloat16* __restrict__ hb, const float* __restrict__ b,
                      float* __restrict__ out, int N, int relu) {
  int lane = threadIdx.x & 63;
  int wid = blockIdx.x * (blockDim.x >> 6) + (threadIdx.x >> 6);
  int nw = gridDim.x * (blockDim.x >> 6);
  float bv = b[lane];
  for (int n = wid; n < N; n += nw) {
    int r0 = roff[n], r1 = roff[n + 1];
    float adn = adb[n];
    float acc = 0.f, denl = 0.f;
    for (int base = r0; base < r1; base += 64) {
      int cnt = min(64, r1 - base);
      int s = 0; float e = 0.f;
      if (lane < cnt) {
        s = csr[base + lane];                  // coalesced 256B
        float l = asb[s] + adn;                // batched random gather (L2-resident)
        l = fmaxf(l, 0.2f * l);                // leaky_relu(0.2)
        e = __expf(l);
      }
      denl += e;
      for (int j = 0; j < cnt; j += 4) {
        int   s0 = __builtin_amdgcn_readlane(s, j);
        int   s1 = __builtin_amdgcn_readlane(s, j + 1);
        int   s2 = __builtin_amdgcn_readlane(s, j + 2);
        int   s3 = __builtin_amdgcn_readlane(s, j + 3);
        float e0 = __uint_as_float(__builtin_amdgcn_readlane(__float_as_uint(e), j));
        float e1 = __uint_as_float(__builtin_amdgcn_readlane(__float_as_uint(e), j + 1));
        float e2 = __uint_as_float(__builtin_amdgcn_readlane(__float_as_uint(e), j + 2));
        float e3 = __uint_as_float(__builtin_amdgcn_readlane(__float_as_uint(e), j + 3));
        // 4 independent gathers in flight (e==0 for lanes beyond cnt -> no-op FMA)
        float h0 = __bfloat162float(hb[(size_t)s0 * DHID + lane]);
        float h1 = __bfloat162float(hb[(size_t)s1 * DHID + lane]);
        float h2 = __bfloat162float(hb[(size_t)s2 * DHID + lane]);
        float h3 = __bfloat162float(hb[(size_t)s3 * DHID + lane]);
        acc += e0 * h0; acc += e1 * h1; acc += e2 * h2; acc += e3 * h3;
      }
    }
    float den = denl;
    #pragma unroll
    for (int off = 32; off; off >>= 1) den += __shfl_xor(den, off, 64);
    float o = acc / (den + 1e-16f) + bv;
    if (relu) o = fmaxf(o, 0.f);
    out[(size_t)n * DHID + lane] = o;
  }
}

extern "C" void kernel_launch(void* const* d_in, const int* in_sizes, int n_in,
                              void* d_out, int out_size, void* d_ws, size_t ws_size,
                              hipStream_t stream) {
  const float* x   = (const float*)d_in[0];
  const int*   ei  = (const int*)d_in[1];
  const float* W1  = (const float*)d_in[2];
  const float* as1 = (const float*)d_in[3];
  const float* ad1 = (const float*)d_in[4];
  const float* b1  = (const float*)d_in[5];
  const float* W2  = (const float*)d_in[6];
  const float* as2 = (const float*)d_in[7];
  const float* ad2 = (const float*)d_in[8];
  const float* b2  = (const float*)d_in[9];

  int N = in_sizes[0] / 128;
  int E = in_sizes[1] / 2;
  const int* srcp = ei;
  const int* dstp = ei + E;

  float* emb  = (float*)d_out;               // output 0: relu(layer1)
  float* out2 = emb + (size_t)N * DHID;      // output 1

  char* w = (char*)d_ws;
  int* roff = (int*)w;  w += (size_t)(N + 1) * 4;
  int* fill = (int*)w;  w += (size_t)N * 4;
  int* csr  = (int*)w;  w += (size_t)(E + N) * 4;
  int* bsum = (int*)w;  w += 512 * 4;
  __hip_bfloat16* hb = (__hip_bfloat16*)w; w += (size_t)N * DHID * 2;
  float* asb = (float*)w; w += (size_t)N * 4;
  float* adb = (float*)w; w += (size_t)N * 4;

  int nb = (N + 1023) / 1024;

  k_init<<<(N + 255) / 256, 256, 0, stream>>>(roff, fill, N);
  k_hist<<<(E + 255) / 256, 256, 0, stream>>>(dstp, roff, E);
  k_scan_block<<<nb, 256, 0, stream>>>(roff, N, bsum);
  k_scan_mid<<<1, 64, 0, stream>>>(bsum, nb);
  k_scan_add<<<(N + 255) / 256, 256, 0, stream>>>(roff, N, bsum, nb);
  k_fill<<<(E + N + 255) / 256, 256, 0, stream>>>(srcp, dstp, roff, fill, csr, E, N);

  // layer 1: h1 = x@W1 ; emb = relu(agg + b1)
  k_gemm<128><<<1024, 256, 0, stream>>>(x, W1, as1, ad1, hb, asb, adb, N);
  k_agg<<<2048, 256, 0, stream>>>(roff, csr, asb, adb, hb, b1, emb, N, 1);
  // layer 2: h2 = emb@W2 ; out2 = agg + b2
  k_gemm<64><<<1024, 256, 0, stream>>>(emb, W2, as2, ad2, hb, asb, adb, N);
  k_agg<<<2048, 256, 0, stream>>>(roff, csr, asb, adb, hb, b2, out2, N, 0);
}

// Round 3
// 334.704 us; speedup vs baseline: 2.0172x; 1.3762x over previous
//
#include <hip/hip_runtime.h>
#include <hip/hip_bf16.h>

#define DHID 64
typedef __attribute__((ext_vector_type(8))) short short8;
typedef __attribute__((ext_vector_type(4))) float f32x4;

static __device__ __forceinline__ short tobf(float f) {
  __hip_bfloat16 h = __float2bfloat16(f);
  return *reinterpret_cast<short*>(&h);
}
static __device__ __forceinline__ float frombf(short s) {
  union { unsigned u; float f; } v; v.u = ((unsigned)(unsigned short)s) << 16; return v.f;
}

// ---------- CSR build ----------
__global__ void k_init(int* __restrict__ cnt, int* __restrict__ fill, int n) {
  int i = blockIdx.x * blockDim.x + threadIdx.x;
  if (i < n) { cnt[i] = 1; fill[i] = 0; }  // cnt=1 pre-counts the self-loop
}

__global__ void k_hist(const int* __restrict__ dst, int* __restrict__ cnt, int E) {
  int i = blockIdx.x * blockDim.x + threadIdx.x;
  if (i < E) atomicAdd(&cnt[dst[i]], 1);
}

__global__ void k_scan_block(int* __restrict__ buf, int n, int* __restrict__ bsum) {
  __shared__ int lds[256];
  int tid = threadIdx.x;
  int base = blockIdx.x * 1024 + tid * 4;
  int a0 = (base + 0) < n ? buf[base + 0] : 0;
  int a1 = (base + 1) < n ? buf[base + 1] : 0;
  int a2 = (base + 2) < n ? buf[base + 2] : 0;
  int a3 = (base + 3) < n ? buf[base + 3] : 0;
  int s = a0 + a1 + a2 + a3;
  lds[tid] = s; __syncthreads();
  for (int off = 1; off < 256; off <<= 1) {
    int t = (tid >= off) ? lds[tid - off] : 0;
    __syncthreads();
    lds[tid] += t;
    __syncthreads();
  }
  int excl = lds[tid] - s;
  if ((base + 0) < n) buf[base + 0] = excl; excl += a0;
  if ((base + 1) < n) buf[base + 1] = excl; excl += a1;
  if ((base + 2) < n) buf[base + 2] = excl; excl += a2;
  if ((base + 3) < n) buf[base + 3] = excl;
  if (tid == 255) bsum[blockIdx.x] = lds[255];
}

__global__ void k_scan_mid(int* __restrict__ bsum, int nb) {
  int lane = threadIdx.x;
  int v0 = (lane < nb) ? bsum[lane] : 0;
  #pragma unroll
  for (int off = 1; off < 64; off <<= 1) { int t = __shfl_up(v0, off, 64); if (lane >= off) v0 += t; }
  int v1 = (64 + lane) < nb ? bsum[64 + lane] : 0;
  #pragma unroll
  for (int off = 1; off < 64; off <<= 1) { int t = __shfl_up(v1, off, 64); if (lane >= off) v1 += t; }
  v1 += __shfl(v0, 63, 64);
  if (lane < nb) bsum[lane] = v0;
  if ((64 + lane) < nb) bsum[64 + lane] = v1;
}

__global__ void k_scan_add(int* __restrict__ buf, int n, const int* __restrict__ bsum, int nb) {
  int i = blockIdx.x * blockDim.x + threadIdx.x;
  if (i < n) { int c = i >> 10; if (c > 0) buf[i] += bsum[c - 1]; }
  if (i == 0) buf[n] = bsum[nb - 1];
}

__global__ void k_fill(const int* __restrict__ src, const int* __restrict__ dst,
                       const int* __restrict__ roff, int* __restrict__ fill,
                       int* __restrict__ csr, int E, int N) {
  int i = blockIdx.x * blockDim.x + threadIdx.x;
  int T = E + N;
  if (i >= T) return;
  int s, d;
  if (i < E) { s = src[i]; d = dst[i]; } else { s = i - E; d = s; }
  int pos = roff[d] + atomicAdd(&fill[d], 1);
  csr[pos] = s;
}

// ---------- prep: x fp32 -> bf16, XOR-swizzled rows (K=128) ----------
__global__ void k_cvt(const float* __restrict__ x, short* __restrict__ xb, int N) {
  int i = blockIdx.x * blockDim.x + threadIdx.x;   // one 8-elem chunk
  int tot = N * 16;
  if (i >= tot) return;
  int row = i >> 4;
  int kc = (i & 15) << 3;
  const float4* xp = (const float4*)(x + (size_t)row * 128 + kc);
  float4 v0 = xp[0], v1 = xp[1];
  short8 o;
  o[0] = tobf(v0.x); o[1] = tobf(v0.y); o[2] = tobf(v0.z); o[3] = tobf(v0.w);
  o[4] = tobf(v1.x); o[5] = tobf(v1.y); o[6] = tobf(v1.z); o[7] = tobf(v1.w);
  int ks = kc ^ ((row & 7) << 3);
  *(short8*)(xb + (size_t)row * 128 + ks) = o;
}

// ---------- prep: W [K][64] -> Wt bf16 [64][K], XOR-swizzled ----------
__global__ void k_prep(const float* __restrict__ W, short* __restrict__ wt, int K) {
  for (int e = threadIdx.x; e < 64 * K; e += blockDim.x) {
    int c = e / K, k = e - c * K;
    wt[c * K + (k ^ ((c & 7) << 3))] = tobf(W[k * 64 + c]);
  }
}

// ---------- MFMA gemm: hb[n][d] = xb[n][:] @ Wt[d][:]^T ; + as/ad dots ----------
// Both A and B fragments use the same (group,reg)->k bijection, so the result is
// independent of the HW operand k-permutation; C/D layout: col=lane&15,
// row=(lane>>4)*4+reg (HW-verified).
template<int K>
__launch_bounds__(256)
__global__ void k_mgemm(const short* __restrict__ xb, const short* __restrict__ wt,
                        const float* __restrict__ a_s, const float* __restrict__ a_d,
                        short* __restrict__ hb, float* __restrict__ asb,
                        float* __restrict__ adb, int N) {
  constexpr int ASZ = 64 * K * 2;          // bytes of A tile (== B tile)
  __shared__ __align__(16) short lds[2 * 64 * K];
  int tid = threadIdx.x;
  int n0 = blockIdx.x * 64;

  const char* ga = (const char*)xb + (size_t)n0 * (K * 2);
  const char* gb = (const char*)wt;
  #pragma unroll
  for (int j = 0; j < (2 * ASZ) / 4096; j++) {
    int d = j * 4096 + tid * 16;
    const char* src = (d < ASZ) ? (ga + d) : (gb + (d - ASZ));
    __builtin_amdgcn_global_load_lds(
        (__attribute__((address_space(1))) const void*)src,
        (__attribute__((address_space(3))) void*)((char*)lds + d), 16, 0, 0);
  }
  __syncthreads();

  int l = tid & 63, w = tid >> 6;
  int c = l & 15, g = l >> 4;
  const short* A = lds;
  const short* B = lds + 64 * K;
  f32x4 acc[4];
  #pragma unroll
  for (int t = 0; t < 4; t++) acc[t] = (f32x4){0.f, 0.f, 0.f, 0.f};

  int arow = 16 * w + c;
  #pragma unroll
  for (int s = 0; s < K / 32; s++) {
    int ke = s * 32 + g * 8;
    short8 af = *(const short8*)(A + arow * K + (ke ^ ((arow & 7) << 3)));
    #pragma unroll
    for (int t = 0; t < 4; t++) {
      int bcol = 16 * t + c;
      short8 bf = *(const short8*)(B + bcol * K + (ke ^ ((bcol & 7) << 3)));
      acc[t] = __builtin_amdgcn_mfma_f32_16x16x32_bf16(af, bf, acc[t], 0, 0, 0);
    }
  }

  float av_s[4], av_d[4];
  #pragma unroll
  for (int t = 0; t < 4; t++) { av_s[t] = a_s[16 * t + c]; av_d[t] = a_d[16 * t + c]; }
  #pragma unroll
  for (int q = 0; q < 4; q++) {
    int row = n0 + 16 * w + g * 4 + q;
    bool ok = row < N;
    float rs = 0.f, rd = 0.f;
    #pragma unroll
    for (int t = 0; t < 4; t++) {
      float v = acc[t][q];
      if (ok) hb[(size_t)row * 64 + 16 * t + c] = tobf(v);
      rs += v * av_s[t]; rd += v * av_d[t];
    }
    #pragma unroll
    for (int off = 1; off < 16; off <<= 1) {
      rs += __shfl_xor(rs, off, 64);
      rd += __shfl_xor(rd, off, 64);
    }
    if (ok && c == 0) { asb[row] = rs; adb[row] = rd; }
  }
}

// ---------- sparse: fused softmax + aggregation, one wave per dst node ----------
__global__ void k_agg(const int* __restrict__ roff, const int* __restrict__ csr,
                      const float* __restrict__ asb, const float* __restrict__ adb,
                      const short* __restrict__ hb, const float* __restrict__ b,
                      float* __restrict__ out, short* __restrict__ outb,
                      int N, int relu) {
  int lane = threadIdx.x & 63;
  int wid = blockIdx.x * (blockDim.x >> 6) + (threadIdx.x >> 6);
  int nw = gridDim.x * (blockDim.x >> 6);
  float bv = b[lane];
  for (int n = wid; n < N; n += nw) {
    int r0 = roff[n], r1 = roff[n + 1];
    float adn = adb[n];
    float acc = 0.f, denl = 0.f;
    for (int base = r0; base < r1; base += 64) {
      int cnt = min(64, r1 - base);
      int s = 0; float e = 0.f;
      if (lane < cnt) {
        s = csr[base + lane];
        float l = asb[s] + adn;
        l = fmaxf(l, 0.2f * l);
        e = __expf(l);
      }
      denl += e;
      for (int j = 0; j < cnt; j += 4) {
        int   s0 = __builtin_amdgcn_readlane(s, j);
        int   s1 = __builtin_amdgcn_readlane(s, j + 1);
        int   s2 = __builtin_amdgcn_readlane(s, j + 2);
        int   s3 = __builtin_amdgcn_readlane(s, j + 3);
        float e0 = __uint_as_float(__builtin_amdgcn_readlane(__float_as_uint(e), j));
        float e1 = __uint_as_float(__builtin_amdgcn_readlane(__float_as_uint(e), j + 1));
        float e2 = __uint_as_float(__builtin_amdgcn_readlane(__float_as_uint(e), j + 2));
        float e3 = __uint_as_float(__builtin_amdgcn_readlane(__float_as_uint(e), j + 3));
        float h0 = frombf(hb[(size_t)s0 * DHID + lane]);
        float h1 = frombf(hb[(size_t)s1 * DHID + lane]);
        float h2 = frombf(hb[(size_t)s2 * DHID + lane]);
        float h3 = frombf(hb[(size_t)s3 * DHID + lane]);
        acc += e0 * h0; acc += e1 * h1; acc += e2 * h2; acc += e3 * h3;
      }
    }
    float den = denl;
    #pragma unroll
    for (int off = 32; off; off >>= 1) den += __shfl_xor(den, off, 64);
    float o = acc / (den + 1e-16f) + bv;
    if (relu) o = fmaxf(o, 0.f);
    out[(size_t)n * DHID + lane] = o;
    if (outb) outb[(size_t)n * DHID + (lane ^ ((n & 7) << 3))] = tobf(o);
  }
}

extern "C" void kernel_launch(void* const* d_in, const int* in_sizes, int n_in,
                              void* d_out, int out_size, void* d_ws, size_t ws_size,
                              hipStream_t stream) {
  const float* x   = (const float*)d_in[0];
  const int*   ei  = (const int*)d_in[1];
  const float* W1  = (const float*)d_in[2];
  const float* as1 = (const float*)d_in[3];
  const float* ad1 = (const float*)d_in[4];
  const float* b1  = (const float*)d_in[5];
  const float* W2  = (const float*)d_in[6];
  const float* as2 = (const float*)d_in[7];
  const float* ad2 = (const float*)d_in[8];
  const float* b2  = (const float*)d_in[9];

  int N = in_sizes[0] / 128;
  int E = in_sizes[1] / 2;
  const int* srcp = ei;
  const int* dstp = ei + E;

  float* emb  = (float*)d_out;
  float* out2 = emb + (size_t)N * DHID;

  char* w = (char*)d_ws;
  auto alloc = [&](size_t bytes) { char* p = w; w += (bytes + 255) & ~(size_t)255; return p; };
  int NR = ((N + 63) / 64) * 64;
  int* roff = (int*)alloc((size_t)(N + 1) * 4);
  int* fill = (int*)alloc((size_t)N * 4);
  int* csr  = (int*)alloc((size_t)(E + N) * 4);
  int* bsum = (int*)alloc(2048);
  short* xb = (short*)alloc((size_t)NR * 128 * 2);
  short* hb = (short*)alloc((size_t)NR * 64 * 2);
  float* asb = (float*)alloc((size_t)N * 4);
  float* adb = (float*)alloc((size_t)N * 4);
  short* wt1 = (short*)alloc(64 * 128 * 2);
  short* wt2 = (short*)alloc(64 * 64 * 2);
  short* eb = xb;  // overlay: xb dead after mgemm1

  int nb = (N + 1023) / 1024;
  int NBLK = (N + 63) / 64;

  k_prep<<<1, 256, 0, stream>>>(W1, wt1, 128);
  k_prep<<<1, 256, 0, stream>>>(W2, wt2, 64);
  k_cvt<<<(N * 16 + 255) / 256, 256, 0, stream>>>(x, xb, N);

  k_init<<<(N + 255) / 256, 256, 0, stream>>>(roff, fill, N);
  k_hist<<<(E + 255) / 256, 256, 0, stream>>>(dstp, roff, E);
  k_scan_block<<<nb, 256, 0, stream>>>(roff, N, bsum);
  k_scan_mid<<<1, 64, 0, stream>>>(bsum, nb);
  k_scan_add<<<(N + 255) / 256, 256, 0, stream>>>(roff, N, bsum, nb);
  k_fill<<<(E + N + 255) / 256, 256, 0, stream>>>(srcp, dstp, roff, fill, csr, E, N);

  k_mgemm<128><<<NBLK, 256, 0, stream>>>(xb, wt1, as1, ad1, hb, asb, adb, N);
  k_agg<<<2048, 256, 0, stream>>>(roff, csr, asb, adb, hb, b1, emb, eb, N, 1);
  k_mgemm<64><<<NBLK, 256, 0, stream>>>(eb, wt2, as2, ad2, hb, asb, adb, N);
  k_agg<<<2048, 256, 0, stream>>>(roff, csr, asb, adb, hb, b2, out2, (short*)nullptr, N, 0);
}

// Round 4
// 298.866 us; speedup vs baseline: 2.2591x; 1.1199x over previous
//
#include <hip/hip_runtime.h>
#include <hip/hip_bf16.h>

#define DHID 64
typedef __attribute__((ext_vector_type(8))) short short8;
typedef __attribute__((ext_vector_type(4))) float f32x4;

static __device__ __forceinline__ short tobf(float f) {
  __hip_bfloat16 h = __float2bfloat16(f);
  return *reinterpret_cast<short*>(&h);
}
static __device__ __forceinline__ float frombf(short s) {
  union { unsigned u; float f; } v; v.u = ((unsigned)(unsigned short)s) << 16; return v.f;
}

// ---------- CSR build ----------
__global__ void k_init(int* __restrict__ cnt, int* __restrict__ fill, int n) {
  int i = blockIdx.x * blockDim.x + threadIdx.x;
  if (i < n) { cnt[i] = 1; fill[i] = 0; }  // cnt=1 pre-counts the self-loop
}

// dst-windowed histogram: window w (= blockIdx%8, XCD-aligned under round-robin
// dispatch) only touches cnt[] lines in its 1/8 dst range -> no cross-XCD line
// ping-pong; edge list re-read per window is cheap sequential/LLC traffic.
__global__ void k_hist(const int* __restrict__ dst, int* __restrict__ cnt, int E, int N) {
  int w = blockIdx.x & 7;
  int lo = (int)(((long)N * w) >> 3);
  int hi = (int)(((long)N * (w + 1)) >> 3);
  int nb = gridDim.x >> 3;
  int bi = blockIdx.x >> 3;
  for (int i = bi * blockDim.x + threadIdx.x; i < E; i += nb * blockDim.x) {
    int d = dst[i];
    if (d >= lo && d < hi) atomicAdd(&cnt[d], 1);
  }
}

__global__ void k_scan_block(int* __restrict__ buf, int n, int* __restrict__ bsum) {
  __shared__ int lds[256];
  int tid = threadIdx.x;
  int base = blockIdx.x * 1024 + tid * 4;
  int a0 = (base + 0) < n ? buf[base + 0] : 0;
  int a1 = (base + 1) < n ? buf[base + 1] : 0;
  int a2 = (base + 2) < n ? buf[base + 2] : 0;
  int a3 = (base + 3) < n ? buf[base + 3] : 0;
  int s = a0 + a1 + a2 + a3;
  lds[tid] = s; __syncthreads();
  for (int off = 1; off < 256; off <<= 1) {
    int t = (tid >= off) ? lds[tid - off] : 0;
    __syncthreads();
    lds[tid] += t;
    __syncthreads();
  }
  int excl = lds[tid] - s;
  if ((base + 0) < n) buf[base + 0] = excl; excl += a0;
  if ((base + 1) < n) buf[base + 1] = excl; excl += a1;
  if ((base + 2) < n) buf[base + 2] = excl; excl += a2;
  if ((base + 3) < n) buf[base + 3] = excl;
  if (tid == 255) bsum[blockIdx.x] = lds[255];
}

__global__ void k_scan_mid(int* __restrict__ bsum, int nb) {
  int lane = threadIdx.x;
  int v0 = (lane < nb) ? bsum[lane] : 0;
  #pragma unroll
  for (int off = 1; off < 64; off <<= 1) { int t = __shfl_up(v0, off, 64); if (lane >= off) v0 += t; }
  int v1 = (64 + lane) < nb ? bsum[64 + lane] : 0;
  #pragma unroll
  for (int off = 1; off < 64; off <<= 1) { int t = __shfl_up(v1, off, 64); if (lane >= off) v1 += t; }
  v1 += __shfl(v0, 63, 64);
  if (lane < nb) bsum[lane] = v0;
  if ((64 + lane) < nb) bsum[64 + lane] = v1;
}

__global__ void k_scan_add(int* __restrict__ buf, int n, const int* __restrict__ bsum, int nb) {
  int i = blockIdx.x * blockDim.x + threadIdx.x;
  if (i < n) { int c = i >> 10; if (c > 0) buf[i] += bsum[c - 1]; }
  if (i == 0) buf[n] = bsum[nb - 1];
}

// dst-windowed CSR fill (same windowing as k_hist): csr/fill scatter confined
// to ~850KB per XCD-resident window -> each dirty line written back once.
__global__ void k_fill(const int* __restrict__ src, const int* __restrict__ dst,
                       const int* __restrict__ roff, int* __restrict__ fill,
                       int* __restrict__ csr, int E, int N) {
  int w = blockIdx.x & 7;
  int lo = (int)(((long)N * w) >> 3);
  int hi = (int)(((long)N * (w + 1)) >> 3);
  int nb = gridDim.x >> 3;
  int bi = blockIdx.x >> 3;
  int T = E + N;
  for (int i = bi * blockDim.x + threadIdx.x; i < T; i += nb * blockDim.x) {
    int s, d;
    if (i < E) { s = src[i]; d = dst[i]; } else { s = i - E; d = s; }
    if (d >= lo && d < hi) {
      int pos = roff[d] + atomicAdd(&fill[d], 1);
      csr[pos] = s;
    }
  }
}

// ---------- prep: x fp32 -> bf16, XOR-swizzled rows (K=128) ----------
__global__ void k_cvt(const float* __restrict__ x, short* __restrict__ xb, int N) {
  int i = blockIdx.x * blockDim.x + threadIdx.x;   // one 8-elem chunk
  int tot = N * 16;
  if (i >= tot) return;
  int row = i >> 4;
  int kc = (i & 15) << 3;
  const float4* xp = (const float4*)(x + (size_t)row * 128 + kc);
  float4 v0 = xp[0], v1 = xp[1];
  short8 o;
  o[0] = tobf(v0.x); o[1] = tobf(v0.y); o[2] = tobf(v0.z); o[3] = tobf(v0.w);
  o[4] = tobf(v1.x); o[5] = tobf(v1.y); o[6] = tobf(v1.z); o[7] = tobf(v1.w);
  int ks = kc ^ ((row & 7) << 3);
  *(short8*)(xb + (size_t)row * 128 + ks) = o;
}

// ---------- prep: W [K][64] -> Wt bf16 [64][K], XOR-swizzled ----------
__global__ void k_prep(const float* __restrict__ W, short* __restrict__ wt, int K) {
  for (int e = threadIdx.x; e < 64 * K; e += blockDim.x) {
    int c = e / K, k = e - c * K;
    wt[c * K + (k ^ ((c & 7) << 3))] = tobf(W[k * 64 + c]);
  }
}

// ---------- MFMA gemm: hb[n][d] = xb[n][:] @ Wt[d][:]^T ; + as/ad dots ----------
template<int K>
__launch_bounds__(256)
__global__ void k_mgemm(const short* __restrict__ xb, const short* __restrict__ wt,
                        const float* __restrict__ a_s, const float* __restrict__ a_d,
                        short* __restrict__ hb, float* __restrict__ asb,
                        float* __restrict__ adb, int N) {
  constexpr int ASZ = 64 * K * 2;          // bytes of A tile (== B tile)
  __shared__ __align__(16) short lds[2 * 64 * K];
  int tid = threadIdx.x;
  int n0 = blockIdx.x * 64;

  const char* ga = (const char*)xb + (size_t)n0 * (K * 2);
  const char* gb = (const char*)wt;
  #pragma unroll
  for (int j = 0; j < (2 * ASZ) / 4096; j++) {
    int d = j * 4096 + tid * 16;
    const char* src = (d < ASZ) ? (ga + d) : (gb + (d - ASZ));
    __builtin_amdgcn_global_load_lds(
        (__attribute__((address_space(1))) const void*)src,
        (__attribute__((address_space(3))) void*)((char*)lds + d), 16, 0, 0);
  }
  __syncthreads();

  int l = tid & 63, w = tid >> 6;
  int c = l & 15, g = l >> 4;
  const short* A = lds;
  const short* B = lds + 64 * K;
  f32x4 acc[4];
  #pragma unroll
  for (int t = 0; t < 4; t++) acc[t] = (f32x4){0.f, 0.f, 0.f, 0.f};

  int arow = 16 * w + c;
  #pragma unroll
  for (int s = 0; s < K / 32; s++) {
    int ke = s * 32 + g * 8;
    short8 af = *(const short8*)(A + arow * K + (ke ^ ((arow & 7) << 3)));
    #pragma unroll
    for (int t = 0; t < 4; t++) {
      int bcol = 16 * t + c;
      short8 bf = *(const short8*)(B + bcol * K + (ke ^ ((bcol & 7) << 3)));
      acc[t] = __builtin_amdgcn_mfma_f32_16x16x32_bf16(af, bf, acc[t], 0, 0, 0);
    }
  }

  float av_s[4], av_d[4];
  #pragma unroll
  for (int t = 0; t < 4; t++) { av_s[t] = a_s[16 * t + c]; av_d[t] = a_d[16 * t + c]; }
  #pragma unroll
  for (int q = 0; q < 4; q++) {
    int row = n0 + 16 * w + g * 4 + q;
    bool ok = row < N;
    float rs = 0.f, rd = 0.f;
    #pragma unroll
    for (int t = 0; t < 4; t++) {
      float v = acc[t][q];
      if (ok) hb[(size_t)row * 64 + 16 * t + c] = tobf(v);
      rs += v * av_s[t]; rd += v * av_d[t];
    }
    #pragma unroll
    for (int off = 1; off < 16; off <<= 1) {
      rs += __shfl_xor(rs, off, 64);
      rd += __shfl_xor(rd, off, 64);
    }
    if (ok && c == 0) { asb[row] = rs; adb[row] = rd; }
  }
}

// ---------- sparse: fused softmax + aggregation, one wave per dst node ----------
__global__ void k_agg(const int* __restrict__ roff, const int* __restrict__ csr,
                      const float* __restrict__ asb, const float* __restrict__ adb,
                      const short* __restrict__ hb, const float* __restrict__ b,
                      float* __restrict__ out, short* __restrict__ outb,
                      int N, int relu) {
  int lane = threadIdx.x & 63;
  int wid = blockIdx.x * (blockDim.x >> 6) + (threadIdx.x >> 6);
  int nw = gridDim.x * (blockDim.x >> 6);
  float bv = b[lane];
  for (int n = wid; n < N; n += nw) {
    int r0 = roff[n], r1 = roff[n + 1];
    float adn = adb[n];
    float acc = 0.f, denl = 0.f;
    for (int base = r0; base < r1; base += 64) {
      int cnt = min(64, r1 - base);
      int s = 0; float e = 0.f;
      if (lane < cnt) {
        s = csr[base + lane];
        float l = asb[s] + adn;
        l = fmaxf(l, 0.2f * l);
        e = __expf(l);
      }
      denl += e;
      // bursts of 8 independent gathers; lanes >= cnt carry s=0,e=0 (no-op FMA
      // on a hot line), so no tail branches needed.
      for (int j = 0; j < cnt; j += 8) {
        #pragma unroll
        for (int k = 0; k < 8; k++) {
          int   sk = __builtin_amdgcn_readlane(s, j + k);
          float ek = __uint_as_float(__builtin_amdgcn_readlane(__float_as_uint(e), j + k));
          acc += ek * frombf(hb[(size_t)sk * DHID + lane]);
        }
      }
    }
    float den = denl;
    #pragma unroll
    for (int off = 32; off; off >>= 1) den += __shfl_xor(den, off, 64);
    float o = acc / (den + 1e-16f) + bv;
    if (relu) o = fmaxf(o, 0.f);
    out[(size_t)n * DHID + lane] = o;
    if (outb) outb[(size_t)n * DHID + (lane ^ ((n & 7) << 3))] = tobf(o);
  }
}

extern "C" void kernel_launch(void* const* d_in, const int* in_sizes, int n_in,
                              void* d_out, int out_size, void* d_ws, size_t ws_size,
                              hipStream_t stream) {
  const float* x   = (const float*)d_in[0];
  const int*   ei  = (const int*)d_in[1];
  const float* W1  = (const float*)d_in[2];
  const float* as1 = (const float*)d_in[3];
  const float* ad1 = (const float*)d_in[4];
  const float* b1  = (const float*)d_in[5];
  const float* W2  = (const float*)d_in[6];
  const float* as2 = (const float*)d_in[7];
  const float* ad2 = (const float*)d_in[8];
  const float* b2  = (const float*)d_in[9];

  int N = in_sizes[0] / 128;
  int E = in_sizes[1] / 2;
  const int* srcp = ei;
  const int* dstp = ei + E;

  float* emb  = (float*)d_out;
  float* out2 = emb + (size_t)N * DHID;

  char* w = (char*)d_ws;
  auto alloc = [&](size_t bytes) { char* p = w; w += (bytes + 255) & ~(size_t)255; return p; };
  int NR = ((N + 63) / 64) * 64;
  int* roff = (int*)alloc((size_t)(N + 1) * 4);
  int* fill = (int*)alloc((size_t)N * 4);
  int* csr  = (int*)alloc((size_t)(E + N) * 4);
  int* bsum = (int*)alloc(2048);
  short* xb = (short*)alloc((size_t)NR * 128 * 2);
  short* hb = (short*)alloc((size_t)NR * 64 * 2);
  float* asb = (float*)alloc((size_t)N * 4);
  float* adb = (float*)alloc((size_t)N * 4);
  short* wt1 = (short*)alloc(64 * 128 * 2);
  short* wt2 = (short*)alloc(64 * 64 * 2);
  short* eb = xb;  // overlay: xb dead after mgemm1

  int nb = (N + 1023) / 1024;
  int NBLK = (N + 63) / 64;

  k_prep<<<1, 256, 0, stream>>>(W1, wt1, 128);
  k_prep<<<1, 256, 0, stream>>>(W2, wt2, 64);
  k_cvt<<<(N * 16 + 255) / 256, 256, 0, stream>>>(x, xb, N);

  k_init<<<(N + 255) / 256, 256, 0, stream>>>(roff, fill, N);
  k_hist<<<512, 256, 0, stream>>>(dstp, roff, E, N);
  k_scan_block<<<nb, 256, 0, stream>>>(roff, N, bsum);
  k_scan_mid<<<1, 64, 0, stream>>>(bsum, nb);
  k_scan_add<<<(N + 255) / 256, 256, 0, stream>>>(roff, N, bsum, nb);
  k_fill<<<1024, 256, 0, stream>>>(srcp, dstp, roff, fill, csr, E, N);

  k_mgemm<128><<<NBLK, 256, 0, stream>>>(xb, wt1, as1, ad1, hb, asb, adb, N);
  k_agg<<<2048, 256, 0, stream>>>(roff, csr, asb, adb, hb, b1, emb, eb, N, 1);
  k_mgemm<64><<<NBLK, 256, 0, stream>>>(eb, wt2, as2, ad2, hb, asb, adb, N);
  k_agg<<<2048, 256, 0, stream>>>(roff, csr, asb, adb, hb, b2, out2, (short*)nullptr, N, 0);
}